// Round 6
// baseline (345.579 us; speedup 1.0000x reference)
//
#include <hip/hip_runtime.h>

typedef __attribute__((ext_vector_type(8))) short bf16x8;
typedef __attribute__((ext_vector_type(4))) short bf16x4;
typedef __attribute__((ext_vector_type(4))) float f32x4;
typedef __attribute__((ext_vector_type(2))) float f32x2;
typedef __attribute__((ext_vector_type(4))) _Float16 f16x4;
typedef __attribute__((ext_vector_type(2))) _Float16 f16x2;

static __device__ __forceinline__ f32x4 MFMA_QK(bf16x8 a, bf16x8 b, f32x4 c) {
  return __builtin_amdgcn_mfma_f32_16x16x32_bf16(a, b, c, 0, 0, 0);
}

#if __has_builtin(__builtin_amdgcn_mfma_f32_16x16x16bf16_1k)
static __device__ __forceinline__ f32x4 MFMA_PV(bf16x4 a, bf16x4 b, f32x4 c) {
  return __builtin_amdgcn_mfma_f32_16x16x16bf16_1k(a, b, c, 0, 0, 0);
}
#define PV_EPILOGUE_GUARD()
#else
static __device__ __forceinline__ f32x4 MFMA_PV(bf16x4 a, bf16x4 b, f32x4 c) {
  asm("v_mfma_f32_16x16x16_bf16 %0, %1, %2, %0" : "+v"(c) : "v"(a), "v"(b));
  return c;
}
#define PV_EPILOGUE_GUARD() asm volatile("s_nop 7\ns_nop 7" :::)
#endif

#if __has_builtin(__builtin_amdgcn_exp2f)
#define EXP2(x) __builtin_amdgcn_exp2f(x)
#else
#define EXP2(x) exp2f(x)
#endif

#define NB   2
#define NSEQ 2048
#define NH   8
#define ND   64
#define FIN  512
#define MD   512
#define NTOK (NB * NSEQ)
#define SCALE_LOG2E 0.18033688011112042f   // (1/sqrt(64)) * log2(e)

#define XB_ELEMS   (NTOK * FIN)            // 2097152 bf16
#define WT_ELEMS   (MD * FIN)              // 262144 bf16
#define HT_ELEMS   (NB * NH * NSEQ * ND)   // 2097152 bf16
#define MB_ELEMS   (NTOK * 32)             // 131072 u64 (bit-packed adj)
#define L_ELEMS    (NB * NH * NSEQ)        // 32768 fp32 per partial
#define O_ELEMS    (NTOK * MD)             // 2097152 f16 per partial
#define NSPLIT_S   8
#define NSPLIT_A   4

static __device__ __forceinline__ unsigned short f2b(float f) {
  union { float f; unsigned u; } c; c.f = f;
  unsigned u = c.u;
  u += 0x7fffu + ((u >> 16) & 1u);   // RNE; inputs finite
  return (unsigned short)(u >> 16);
}

static __device__ __forceinline__ unsigned pack2(float a, float b) {
#if __has_builtin(__builtin_amdgcn_cvt_pk_bf16_f32)
  auto v = __builtin_amdgcn_cvt_pk_bf16_f32(a, b);
  unsigned r; __builtin_memcpy(&r, &v, 4); return r;
#else
  return (unsigned)f2b(a) | ((unsigned)f2b(b) << 16);
#endif
}

// ============================================================================
// Convert x -> bf16 (xb) and W -> bf16 transposed (wt[n][k]).
// ============================================================================
__global__ __launch_bounds__(256)
void cvt_kernel(const float* __restrict__ x, const float* __restrict__ W,
                unsigned short* __restrict__ xb, unsigned short* __restrict__ wt) {
  const int t = threadIdx.x;
  if (blockIdx.x < 2048) {
    size_t i = ((size_t)blockIdx.x * 256 + t) * 4;
    f32x4 v = *(const f32x4*)(x + i);
    ushort4 o = make_ushort4(f2b(v[0]), f2b(v[1]), f2b(v[2]), f2b(v[3]));
    *(ushort4*)(xb + i) = o;
  } else {
    int j = ((int)(blockIdx.x - 2048) * 256 + t) * 4;
    int k = j >> 9, n = j & 511;
    f32x4 v = *(const f32x4*)(W + (size_t)k * MD + n);
    wt[(size_t)(n + 0) * FIN + k] = f2b(v[0]);
    wt[(size_t)(n + 1) * FIN + k] = f2b(v[1]);
    wt[(size_t)(n + 2) * FIN + k] = f2b(v[2]);
    wt[(size_t)(n + 3) * FIN + k] = f2b(v[3]);
  }
}

// ============================================================================
// Bit-pack adj: mb[row*32 + w] = ballot(adj[row][w*64 + lane] != 0).
// ============================================================================
__global__ __launch_bounds__(1024)
void maskpack_kernel(const int* __restrict__ adj, unsigned long long* __restrict__ mb) {
  const int t = threadIdx.x;
  const int gw = blockIdx.x * 16 + (t >> 6);     // gw = row*32 + w64
  const int row = gw >> 5, w64 = gw & 31;
  int a = adj[(size_t)row * NSEQ + w64 * 64 + (t & 63)];
  unsigned long long m = __ballot(a != 0);
  if ((t & 63) == 0) mb[gw] = m;
}

// ============================================================================
// Projection GEMM (bf16 in, bf16 out in 2 layouts). 64x64 tile, BK=64.
// ============================================================================
__global__ __launch_bounds__(256, 2)
void proj_kernel(const unsigned short* __restrict__ xb, const unsigned short* __restrict__ wt,
                 const float* __restrict__ bias,
                 unsigned short* __restrict__ h_t, unsigned short* __restrict__ h_d) {
  __shared__ __align__(16) unsigned short sA[64][72];
  __shared__ __align__(16) unsigned short sB[64][72];
  const int t = threadIdx.x;
  const int w = t >> 6, L = t & 63, l15 = L & 15, qd = L >> 4;
  const int bm = blockIdx.x, bn = blockIdx.y;
  const int r = t >> 3, c8 = (t & 7) * 8;
  const f32x4 ZERO4 = {0.f, 0.f, 0.f, 0.f};

  f32x4 acc[4];
  #pragma unroll
  for (int q = 0; q < 4; ++q) acc[q] = ZERO4;

  for (int ks = 0; ks < FIN; ks += 64) {
    __syncthreads();
    *(bf16x8*)&sA[r][c8]      = *(const bf16x8*)&xb[(size_t)(bm*64 + r)      * FIN + ks + c8];
    *(bf16x8*)&sA[r + 32][c8] = *(const bf16x8*)&xb[(size_t)(bm*64 + r + 32) * FIN + ks + c8];
    *(bf16x8*)&sB[r][c8]      = *(const bf16x8*)&wt[(size_t)(bn*64 + r)      * FIN + ks + c8];
    *(bf16x8*)&sB[r + 32][c8] = *(const bf16x8*)&wt[(size_t)(bn*64 + r + 32) * FIN + ks + c8];
    __syncthreads();
    #pragma unroll
    for (int kk = 0; kk < 2; ++kk) {
      bf16x8 af = *(const bf16x8*)&sA[16*w + l15][kk*32 + qd*8];
      #pragma unroll
      for (int q = 0; q < 4; ++q) {
        bf16x8 bf = *(const bf16x8*)&sB[16*q + l15][kk*32 + qd*8];
        acc[q] = MFMA_QK(af, bf, acc[q]);
      }
    }
  }

  #pragma unroll
  for (int q = 0; q < 4; ++q) {
    int feat = bn * 64 + 16 * q + l15;
    int hh = feat >> 6, dd = feat & 63;
    float bv = bias[feat];
    int token0 = bm * 64 + 16 * w + qd * 4;   // 4-aligned, never crosses b
    unsigned short pk[4];
    #pragma unroll
    for (int rr = 0; rr < 4; ++rr) {
      float v = acc[q][rr] + bv;
      unsigned short bb = f2b(v);
      int token = token0 + rr;
      int b = token >> 11, n = token & 2047;
      h_t[((size_t)(b * NH + hh) * NSEQ + n) * ND + dd] = bb;
      pk[rr] = bb;
    }
    int b = token0 >> 11, n0 = token0 & 2047;
    *(ushort4*)&h_d[((size_t)(b * NH + hh) * ND + dd) * NSEQ + n0] =
        make_ushort4(pk[0], pk[1], pk[2], pk[3]);
  }
}

// ============================================================================
// Stats: l_part[e][b][h][n] = sum over column-eighth e of mask*exp(s/8).
// No LDS, no barriers. Grid (128,8) = 4 blocks/CU.
// ============================================================================
__global__ __launch_bounds__(512, 4)
void stats_kernel(const unsigned short* __restrict__ h_t,
                  const unsigned long long* __restrict__ mb,
                  float* __restrict__ l_part) {
  const int t = threadIdx.x;
  const int h = t >> 6, L = t & 63, l15 = L & 15, qd = L >> 4;
  const int u = blockIdx.x & 7;
  const int b = u >> 2;
  const int rblk = ((int)blockIdx.x >> 3) * 4 + (u & 3);
  const int q8 = blockIdx.y;
  const int n0 = rblk * 32;
  const int qd4 = qd * 4;
  const f32x4 ZERO4 = {0.f, 0.f, 0.f, 0.f};

  const unsigned short* hb = h_t + (size_t)(b * NH + h) * NSEQ * ND;
  bf16x8 qf[2][2];
  #pragma unroll
  for (int g = 0; g < 2; ++g)
    #pragma unroll
    for (int kk = 0; kk < 2; ++kk)
      qf[g][kk] = *(const bf16x8*)&hb[(size_t)(n0 + g*16 + l15) * ND + kk*32 + qd*8];

  float lacc[2] = {0.f, 0.f};
  const unsigned long long* mrow = mb + (((size_t)(b * NSEQ + n0 + l15)) << 5) + q8 * 4;

  for (int it = 0; it < 4; ++it) {
    const int c0 = q8 * 256 + it * 64;
    unsigned mlo[2], mhi[2];
    #pragma unroll
    for (int g = 0; g < 2; ++g) {
      unsigned long long m = mrow[g * 512 + it];   // row += 16 -> +512 u64
      mlo[g] = (unsigned)m; mhi[g] = (unsigned)(m >> 32);
    }
    #pragma unroll
    for (int cc = 0; cc < 4; ++cc) {
      const unsigned short* kp = &hb[(size_t)(c0 + cc*16 + l15) * ND + qd*8];
      bf16x8 kf0 = *(const bf16x8*)kp;
      bf16x8 kf1 = *(const bf16x8*)(kp + 32);
      #pragma unroll
      for (int g = 0; g < 2; ++g) {
        f32x4 s = MFMA_QK(kf0, qf[g][0], ZERO4);
        s = MFMA_QK(kf1, qf[g][1], s);
        unsigned nib = (((cc & 2) ? mhi[g] : mlo[g]) >> (((cc & 1) << 4) + qd4)) & 0xFu;
        #pragma unroll
        for (int rr = 0; rr < 4; ++rr) {
          float e = EXP2(s[rr] * SCALE_LOG2E);
          lacc[g] += (nib & (1u << rr)) ? e : 0.f;
        }
      }
    }
  }
  #pragma unroll
  for (int g = 0; g < 2; ++g) {
    float v = lacc[g];
    v += __shfl_xor(v, 16);
    v += __shfl_xor(v, 32);
    if (L < 16)
      l_part[(size_t)q8 * L_ELEMS + (size_t)(b * NH + h) * NSEQ + n0 + g*16 + L] = v;
  }
}

// ============================================================================
// Attention: 16 query rows/block (no g loop), grid (256,4) = 1024 blocks =
// 4 blocks/CU = 32 waves/CU. S^T->P^T in registers, PV = V^T P^T;
// mean via LDS once/iter. launch_bounds (512,4): VGPR cap 128 (r4 spill bug).
// ============================================================================
__global__ __launch_bounds__(512, 4)
void attn_kernel(const unsigned short* __restrict__ h_t, const unsigned short* __restrict__ h_d,
                 const unsigned long long* __restrict__ mb, const float* __restrict__ l_part,
                 _Float16* __restrict__ o_part, float* __restrict__ mean_out) {
  const int t = threadIdx.x;
  const int h = t >> 6, L = t & 63, l15 = L & 15, qd = L >> 4;
  const int u = blockIdx.x & 7;
  const int b = u >> 2;
  const int rblk = ((int)blockIdx.x >> 3) * 4 + (u & 3);   // 0..127
  const int quarter = blockIdx.y;
  const int n0 = rblk * 16;
  const int qd4 = qd * 4;
  __shared__ __align__(16) unsigned short s_part[8][16][72];   // 18432 B
  const f32x4 ZERO4 = {0.f, 0.f, 0.f, 0.f};

  const unsigned short* hb = h_t + (size_t)(b * NH + h) * NSEQ * ND;
  const unsigned short* vb = h_d + (size_t)(b * NH + h) * ND * NSEQ;

  bf16x8 qf[2];
  #pragma unroll
  for (int kk = 0; kk < 2; ++kk)
    qf[kk] = *(const bf16x8*)&hb[(size_t)(n0 + l15) * ND + kk*32 + qd*8];

  float linv;
  {
    size_t idx = (size_t)(b * NH + h) * NSEQ + n0 + l15;
    float ls = 0.f;
    #pragma unroll
    for (int q = 0; q < NSPLIT_S; ++q) ls += l_part[(size_t)q * L_ELEMS + idx];
    linv = -__log2f(ls);
  }

  f32x4 oacc[4];
  #pragma unroll
  for (int dc = 0; dc < 4; ++dc) oacc[dc] = ZERO4;

  const unsigned long long* mrow = mb + (((size_t)(b * NSEQ + n0 + l15)) << 5) + quarter * 8;

  for (int it = 0; it < 8; ++it) {
    const int c0 = quarter * 512 + it * 64;
    unsigned long long m = mrow[it];
    unsigned mlo = (unsigned)m, mhi = (unsigned)(m >> 32);
    __syncthreads();   // A: previous iter's mean reads of s_part are done
    #pragma unroll
    for (int cc = 0; cc < 4; ++cc) {
      const int ccol = c0 + cc * 16;
      const unsigned short* kp = &hb[(size_t)(ccol + l15) * ND + qd*8];
      bf16x8 kf0 = *(const bf16x8*)kp;
      bf16x8 kf1 = *(const bf16x8*)(kp + 32);
      bf16x4 va[4];
      #pragma unroll
      for (int dc = 0; dc < 4; ++dc)
        va[dc] = *(const bf16x4*)&vb[(size_t)(dc*16 + l15) * NSEQ + ccol + qd4];
      f32x4 s = MFMA_QK(kf0, qf[0], ZERO4);
      s = MFMA_QK(kf1, qf[1], s);
      unsigned nib = (((cc & 2) ? mhi : mlo) >> (((cc & 1) << 4) + qd4)) & 0xFu;
      f32x4 p;
      #pragma unroll
      for (int rr = 0; rr < 4; ++rr) {
        float e = EXP2(__builtin_fmaf(s[rr], SCALE_LOG2E, linv));
        p[rr] = (nib & (1u << rr)) ? e : 0.f;
      }
      union { unsigned u2[2]; bf16x4 v4; uint2 d; } pk;
      pk.u2[0] = pack2(p[0], p[1]);
      pk.u2[1] = pack2(p[2], p[3]);
      *(uint2*)&s_part[h][l15][cc*16 + qd4] = pk.d;
      #pragma unroll
      for (int dc = 0; dc < 4; ++dc)
        oacc[dc] = MFMA_PV(va[dc], pk.v4, oacc[dc]);
    }
    __syncthreads();   // C: s_part complete
    if (t < 256) {
      const int mr = t >> 4, mc4 = (t & 15) * 4;
      f32x4 macc = ZERO4;
      #pragma unroll
      for (int hh = 0; hh < 8; ++hh) {
        uint2 pv = *(const uint2*)&s_part[hh][mr][mc4];
        union { unsigned u; float f; } a0, a1, a2, a3;
        a0.u = pv.x << 16; a1.u = pv.x & 0xffff0000u;
        a2.u = pv.y << 16; a3.u = pv.y & 0xffff0000u;
        macc[0] += a0.f; macc[1] += a1.f; macc[2] += a2.f; macc[3] += a3.f;
      }
      macc *= 0.125f;
      *(f32x4*)&mean_out[((size_t)b * NSEQ + n0 + mr) * NSEQ + c0 + mc4] = macc;
    }
  }

  PV_EPILOGUE_GUARD();
  {
    size_t token = (size_t)b * NSEQ + n0 + l15;
    #pragma unroll
    for (int dc = 0; dc < 4; ++dc) {
      f16x4 o;
      #pragma unroll
      for (int rr = 0; rr < 4; ++rr) o[rr] = (_Float16)oacc[dc][rr];
      *(f16x4*)&o_part[(size_t)quarter * O_ELEMS + token * MD + h*64 + dc*16 + qd4] = o;
    }
  }
}

// ============================================================================
// LayerNorm over model dim; sums the 4 fp16 column-quarter O partials.
// ============================================================================
__global__ __launch_bounds__(256)
void ln_kernel(const _Float16* __restrict__ o_part, const float* __restrict__ gamma,
               const float* __restrict__ beta, float* __restrict__ out) {
  const int row = blockIdx.x, t = threadIdx.x;
  const size_t base = (size_t)row * MD + 2 * t;
  float v0 = 0.f, v1 = 0.f;
  #pragma unroll
  for (int q = 0; q < NSPLIT_A; ++q) {
    f16x2 x = *(const f16x2*)&o_part[(size_t)q * O_ELEMS + base];
    v0 += (float)x[0]; v1 += (float)x[1];
  }
  float s = v0 + v1, sq = v0 * v0 + v1 * v1;
  for (int m = 1; m < 64; m <<= 1) { s += __shfl_xor(s, m); sq += __shfl_xor(sq, m); }
  __shared__ float rs[4], rq[4];
  if ((t & 63) == 0) { rs[t >> 6] = s; rq[t >> 6] = sq; }
  __syncthreads();
  s = rs[0] + rs[1] + rs[2] + rs[3];
  sq = rq[0] + rq[1] + rq[2] + rq[3];
  float mu = s * (1.f / MD);
  float var = sq * (1.f / MD) - mu * mu;
  float rstd = rsqrtf(var + 1e-5f);
  f32x2 g2 = *(const f32x2*)&gamma[2 * t];
  f32x2 b2 = *(const f32x2*)&beta[2 * t];
  f32x2 o;
  o[0] = (v0 - mu) * rstd * g2[0] + b2[0];
  o[1] = (v1 - mu) * rstd * g2[1] + b2[1];
  *(f32x2*)&out[base] = o;
}

// ============================================================================
extern "C" void kernel_launch(void* const* d_in, const int* in_sizes, int n_in,
                              void* d_out, int out_size, void* d_ws, size_t ws_size,
                              hipStream_t stream) {
  const float* x     = (const float*)d_in[0];
  const int*   adj   = (const int*)d_in[1];
  const float* W     = (const float*)d_in[2];
  const float* Wb    = (const float*)d_in[3];
  const float* gamma = (const float*)d_in[4];
  const float* beta  = (const float*)d_in[5];
  float* out = (float*)d_out;

  unsigned short* xb  = (unsigned short*)d_ws;              // 4 MB
  unsigned short* wt  = xb + XB_ELEMS;                      // 0.5 MB
  unsigned short* h_t = wt + WT_ELEMS;                      // 4 MB
  unsigned short* h_d = h_t + HT_ELEMS;                     // 4 MB
  unsigned long long* mbits = (unsigned long long*)(h_d + HT_ELEMS);  // 1 MB
  float* l_part = (float*)(mbits + MB_ELEMS);               // 1 MB (8 partials)
  _Float16* o_part = (_Float16*)(l_part + NSPLIT_S * L_ELEMS);  // 16 MB (4 partials)

  cvt_kernel<<<2304, 256, 0, stream>>>(x, W, xb, wt);
  maskpack_kernel<<<8192, 1024, 0, stream>>>(adj, mbits);
  proj_kernel<<<dim3(64, 8), 256, 0, stream>>>(xb, wt, Wb, h_t, h_d);
  stats_kernel<<<dim3(128, NSPLIT_S), 512, 0, stream>>>(h_t, mbits, l_part);
  attn_kernel<<<dim3(256, NSPLIT_A), 512, 0, stream>>>(h_t, h_d, mbits, l_part, o_part,
                                                       out + (size_t)NTOK * MD);
  ln_kernel<<<NTOK, 256, 0, stream>>>(o_part, gamma, beta, out);
}

// Round 7
// 185.988 us; speedup vs baseline: 1.8581x; 1.8581x over previous
//
#include <hip/hip_runtime.h>

typedef __attribute__((ext_vector_type(8))) short bf16x8;
typedef __attribute__((ext_vector_type(4))) short bf16x4;
typedef __attribute__((ext_vector_type(4))) float f32x4;
typedef __attribute__((ext_vector_type(2))) float f32x2;
typedef __attribute__((ext_vector_type(4))) _Float16 f16x4;
typedef __attribute__((ext_vector_type(2))) _Float16 f16x2;

static __device__ __forceinline__ f32x4 MFMA_QK(bf16x8 a, bf16x8 b, f32x4 c) {
  return __builtin_amdgcn_mfma_f32_16x16x32_bf16(a, b, c, 0, 0, 0);
}

#if __has_builtin(__builtin_amdgcn_mfma_f32_16x16x16bf16_1k)
static __device__ __forceinline__ f32x4 MFMA_PV(bf16x4 a, bf16x4 b, f32x4 c) {
  return __builtin_amdgcn_mfma_f32_16x16x16bf16_1k(a, b, c, 0, 0, 0);
}
#define PV_EPILOGUE_GUARD()
#else
static __device__ __forceinline__ f32x4 MFMA_PV(bf16x4 a, bf16x4 b, f32x4 c) {
  asm("v_mfma_f32_16x16x16_bf16 %0, %1, %2, %0" : "+v"(c) : "v"(a), "v"(b));
  return c;
}
#define PV_EPILOGUE_GUARD() asm volatile("s_nop 7\ns_nop 7" :::)
#endif

#if __has_builtin(__builtin_amdgcn_exp2f)
#define EXP2(x) __builtin_amdgcn_exp2f(x)
#else
#define EXP2(x) exp2f(x)
#endif

#define NB   2
#define NSEQ 2048
#define NH   8
#define ND   64
#define FIN  512
#define MD   512
#define NTOK (NB * NSEQ)
#define SCALE_LOG2E 0.18033688011112042f   // (1/sqrt(64)) * log2(e)

#define XB_ELEMS   (NTOK * FIN)            // 2097152 bf16
#define WT_ELEMS   (MD * FIN)              // 262144 bf16
#define HH_ELEMS   (NB * NH * NSEQ * ND)   // 2097152 bf16 (h_c / h_v each)
#define MB_ELEMS   (NTOK * 32)             // 131072 u64 (bit-packed adj)
#define L_ELEMS    (NB * NH * NSEQ)        // 32768 fp32 per partial
#define O_ELEMS    (NTOK * MD)             // 2097152 f16 per partial
#define NSPLIT_S   8
#define NSPLIT_A   4

static __device__ __forceinline__ unsigned short f2b(float f) {
  union { float f; unsigned u; } c; c.f = f;
  unsigned u = c.u;
  u += 0x7fffu + ((u >> 16) & 1u);   // RNE; inputs finite
  return (unsigned short)(u >> 16);
}

static __device__ __forceinline__ unsigned pack2(float a, float b) {
#if __has_builtin(__builtin_amdgcn_cvt_pk_bf16_f32)
  auto v = __builtin_amdgcn_cvt_pk_bf16_f32(a, b);
  unsigned r; __builtin_memcpy(&r, &v, 4); return r;
#else
  return (unsigned)f2b(a) | ((unsigned)f2b(b) << 16);
#endif
}

static __device__ __forceinline__ void split8(bf16x8 v, bf16x4* a, bf16x4* b) {
  union { bf16x8 w; bf16x4 h[2]; } u; u.w = v; *a = u.h[0]; *b = u.h[1];
}

// ============================================================================
// Convert x -> bf16 (xb) and W -> bf16 transposed (wt[n][k]).
// ============================================================================
__global__ __launch_bounds__(256)
void cvt_kernel(const float* __restrict__ x, const float* __restrict__ W,
                unsigned short* __restrict__ xb, unsigned short* __restrict__ wt) {
  const int t = threadIdx.x;
  if (blockIdx.x < 2048) {
    size_t i = ((size_t)blockIdx.x * 256 + t) * 4;
    f32x4 v = *(const f32x4*)(x + i);
    ushort4 o = make_ushort4(f2b(v[0]), f2b(v[1]), f2b(v[2]), f2b(v[3]));
    *(ushort4*)(xb + i) = o;
  } else {
    int j = ((int)(blockIdx.x - 2048) * 256 + t) * 4;
    int k = j >> 9, n = j & 511;
    f32x4 v = *(const f32x4*)(W + (size_t)k * MD + n);
    wt[(size_t)(n + 0) * FIN + k] = f2b(v[0]);
    wt[(size_t)(n + 1) * FIN + k] = f2b(v[1]);
    wt[(size_t)(n + 2) * FIN + k] = f2b(v[2]);
    wt[(size_t)(n + 3) * FIN + k] = f2b(v[3]);
  }
}

// ============================================================================
// Bit-pack adj: mb[row*32 + w] = ballot(adj[row][w*64 + lane] != 0).
// ============================================================================
__global__ __launch_bounds__(1024)
void maskpack_kernel(const int* __restrict__ adj, unsigned long long* __restrict__ mb) {
  const int t = threadIdx.x;
  const int gw = blockIdx.x * 16 + (t >> 6);     // gw = row*32 + w64
  const int row = gw >> 5, w64 = gw & 31;
  int a = adj[(size_t)row * NSEQ + w64 * 64 + (t & 63)];
  unsigned long long m = __ballot(a != 0);
  if ((t & 63) == 0) mb[gw] = m;
}

// ============================================================================
// Projection GEMM -> h in MFMA-fragment layouts:
//  h_c[b][h][cb][chunk][lane][8]: QK A/B-frag; lane (qd,l15) holds
//     h[col = cb*16+l15][d = chunk*32 + qd*8 .. +8)   (1024B coalesced/load)
//  h_v[b][h][cb][pair][lane][8]: PV A-frag pairs; lane (qd,l15) holds
//     { V[d=2p*16+l15][c=cb*16+qd*4..+4), V[d=(2p+1)*16+l15][same cols] }
// ============================================================================
__global__ __launch_bounds__(256, 2)
void proj_kernel(const unsigned short* __restrict__ xb, const unsigned short* __restrict__ wt,
                 const float* __restrict__ bias,
                 unsigned short* __restrict__ h_c, unsigned short* __restrict__ h_v) {
  __shared__ __align__(16) unsigned short sA[64][72];
  __shared__ __align__(16) unsigned short sB[64][72];
  const int t = threadIdx.x;
  const int w = t >> 6, L = t & 63, l15 = L & 15, qd = L >> 4;
  const int bm = blockIdx.x, bn = blockIdx.y;
  const int r = t >> 3, c8 = (t & 7) * 8;
  const f32x4 ZERO4 = {0.f, 0.f, 0.f, 0.f};

  f32x4 acc[4];
  #pragma unroll
  for (int q = 0; q < 4; ++q) acc[q] = ZERO4;

  for (int ks = 0; ks < FIN; ks += 64) {
    __syncthreads();
    *(bf16x8*)&sA[r][c8]      = *(const bf16x8*)&xb[(size_t)(bm*64 + r)      * FIN + ks + c8];
    *(bf16x8*)&sA[r + 32][c8] = *(const bf16x8*)&xb[(size_t)(bm*64 + r + 32) * FIN + ks + c8];
    *(bf16x8*)&sB[r][c8]      = *(const bf16x8*)&wt[(size_t)(bn*64 + r)      * FIN + ks + c8];
    *(bf16x8*)&sB[r + 32][c8] = *(const bf16x8*)&wt[(size_t)(bn*64 + r + 32) * FIN + ks + c8];
    __syncthreads();
    #pragma unroll
    for (int kk = 0; kk < 2; ++kk) {
      bf16x8 af = *(const bf16x8*)&sA[16*w + l15][kk*32 + qd*8];
      #pragma unroll
      for (int q = 0; q < 4; ++q) {
        bf16x8 bf = *(const bf16x8*)&sB[16*q + l15][kk*32 + qd*8];
        acc[q] = MFMA_QK(af, bf, acc[q]);
      }
    }
  }

  #pragma unroll
  for (int q = 0; q < 4; ++q) {
    int feat = bn * 64 + 16 * q + l15;
    int hh = feat >> 6, d = feat & 63;
    float bv = bias[feat];
    int token0 = bm * 64 + 16 * w + qd * 4;   // 4-aligned, never crosses b
    int b0 = token0 >> 11, nn0 = token0 & 2047;
    size_t hcb = (size_t)(b0 * NH + hh) * HH_ELEMS / (NB * NH);  // per-(b,h) slab of 131072
    unsigned short pk[4];
    #pragma unroll
    for (int rr = 0; rr < 4; ++rr) {
      float v = acc[q][rr] + bv;
      unsigned short bb = f2b(v);
      int n = nn0 + rr;
      // h_c scatter: cb = n>>4, lane = qd_c*16 + (n&15), elem = d&7
      size_t idx = hcb + ((size_t)(n >> 4)) * 1024 + (d >> 5) * 512
                 + ((d >> 3) & 3) * 128 + (n & 15) * 8 + (d & 7);
      h_c[idx] = bb;
      pk[rr] = bb;
    }
    // h_v: 4 consecutive cols -> one ushort4; pair p = (d>>4)>>1, half = ((d>>4)&1)*4
    size_t vidx = hcb + ((size_t)(nn0 >> 4)) * 1024 + ((d >> 5)) * 512
                + (((nn0 >> 2) & 3) * 16 + (d & 15)) * 8 + ((d >> 4) & 1) * 4;
    *(ushort4*)&h_v[vidx] = make_ushort4(pk[0], pk[1], pk[2], pk[3]);
  }
}

// ============================================================================
// Stats: l_part[e][b][h][n] = sum over column-eighth e of mask*exp(s/8).
// No LDS, no barriers; all loads lane-contiguous from h_c. Grid (128,8).
// ============================================================================
__global__ __launch_bounds__(512, 4)
void stats_kernel(const unsigned short* __restrict__ h_c,
                  const unsigned long long* __restrict__ mb,
                  float* __restrict__ l_part) {
  const int t = threadIdx.x;
  const int h = t >> 6, L = t & 63, l15 = L & 15, qd = L >> 4;
  const int u = blockIdx.x & 7;
  const int b = u >> 2;
  const int rblk = ((int)blockIdx.x >> 3) * 4 + (u & 3);
  const int q8 = blockIdx.y;
  const int n0 = rblk * 32;
  const int qd4 = qd * 4;
  const int lane8 = L * 8;
  const f32x4 ZERO4 = {0.f, 0.f, 0.f, 0.f};

  const unsigned short* hc = h_c + (size_t)(b * NH + h) * (NSEQ * ND);
  bf16x8 qf[2][2];
  #pragma unroll
  for (int g = 0; g < 2; ++g)
    #pragma unroll
    for (int kk = 0; kk < 2; ++kk)
      qf[g][kk] = *(const bf16x8*)&hc[((n0 >> 4) + g) * 1024 + kk * 512 + lane8];

  float lacc[2] = {0.f, 0.f};
  const unsigned long long* mrow = mb + (((size_t)(b * NSEQ + n0 + l15)) << 5) + q8 * 4;

  for (int it = 0; it < 4; ++it) {
    const int c0 = q8 * 256 + it * 64;
    unsigned mlo[2], mhi[2];
    #pragma unroll
    for (int g = 0; g < 2; ++g) {
      unsigned long long m = mrow[g * 512 + it];   // row += 16 -> +512 u64
      mlo[g] = (unsigned)m; mhi[g] = (unsigned)(m >> 32);
    }
    #pragma unroll
    for (int cc = 0; cc < 4; ++cc) {
      const int cb = (c0 >> 4) + cc;
      bf16x8 kf0 = *(const bf16x8*)&hc[cb * 1024 + lane8];
      bf16x8 kf1 = *(const bf16x8*)&hc[cb * 1024 + 512 + lane8];
      #pragma unroll
      for (int g = 0; g < 2; ++g) {
        f32x4 s = MFMA_QK(kf0, qf[g][0], ZERO4);
        s = MFMA_QK(kf1, qf[g][1], s);
        unsigned nib = (((cc & 2) ? mhi[g] : mlo[g]) >> (((cc & 1) << 4) + qd4)) & 0xFu;
        #pragma unroll
        for (int rr = 0; rr < 4; ++rr) {
          float e = EXP2(s[rr] * SCALE_LOG2E);
          lacc[g] += (nib & (1u << rr)) ? e : 0.f;
        }
      }
    }
  }
  #pragma unroll
  for (int g = 0; g < 2; ++g) {
    float v = lacc[g];
    v += __shfl_xor(v, 16);
    v += __shfl_xor(v, 32);
    if (L < 16)
      l_part[(size_t)q8 * L_ELEMS + (size_t)(b * NH + h) * NSEQ + n0 + g*16 + L] = v;
  }
}

// ============================================================================
// Attention: 32 rows/block (g=2), all frag loads lane-contiguous (h_c, h_v),
// double-buffered s_part -> ONE barrier/iter. Grid (128,4), 512 threads.
// launch_bounds (512,4): VGPR cap 128 (r4 taught: never demand 8 waves/EU).
// ============================================================================
__global__ __launch_bounds__(512, 4)
void attn_kernel(const unsigned short* __restrict__ h_c, const unsigned short* __restrict__ h_v,
                 const unsigned long long* __restrict__ mb, const float* __restrict__ l_part,
                 _Float16* __restrict__ o_part, float* __restrict__ mean_out) {
  const int t = threadIdx.x;
  const int h = t >> 6, L = t & 63, l15 = L & 15, qd = L >> 4;
  const int u = blockIdx.x & 7;
  const int b = u >> 2;
  const int rblk = ((int)blockIdx.x >> 3) * 4 + (u & 3);
  const int quarter = blockIdx.y;
  const int n0 = rblk * 32;
  const int qd4 = qd * 4;
  const int lane8 = L * 8;
  __shared__ __align__(16) unsigned short s_part[2][8][32][72];   // 73728 B
  const f32x4 ZERO4 = {0.f, 0.f, 0.f, 0.f};

  const unsigned short* hc = h_c + (size_t)(b * NH + h) * (NSEQ * ND);
  const unsigned short* hv = h_v + (size_t)(b * NH + h) * (NSEQ * ND);

  bf16x8 qf[2][2];
  #pragma unroll
  for (int g = 0; g < 2; ++g)
    #pragma unroll
    for (int kk = 0; kk < 2; ++kk)
      qf[g][kk] = *(const bf16x8*)&hc[((n0 >> 4) + g) * 1024 + kk * 512 + lane8];

  float linv[2];
  #pragma unroll
  for (int g = 0; g < 2; ++g) {
    size_t idx = (size_t)(b * NH + h) * NSEQ + n0 + g*16 + l15;
    float ls = 0.f;
    #pragma unroll
    for (int q = 0; q < NSPLIT_S; ++q) ls += l_part[(size_t)q * L_ELEMS + idx];
    linv[g] = -__log2f(ls);
  }

  f32x4 oacc[2][4];
  #pragma unroll
  for (int g = 0; g < 2; ++g)
    #pragma unroll
    for (int dc = 0; dc < 4; ++dc) oacc[g][dc] = ZERO4;

  const int cr = t >> 4, cc4 = (t & 15) * 4;
  const unsigned long long* mrow = mb + (((size_t)(b * NSEQ + n0 + l15)) << 5) + quarter * 8;

  for (int it = 0; it < 8; ++it) {
    const int c0 = quarter * 512 + it * 64;
    const int buf = it & 1;
    unsigned mlo[2], mhi[2];
    #pragma unroll
    for (int g = 0; g < 2; ++g) {
      unsigned long long m = mrow[g * 512 + it];
      mlo[g] = (unsigned)m; mhi[g] = (unsigned)(m >> 32);
    }
    #pragma unroll
    for (int cc = 0; cc < 4; ++cc) {
      const int cb = (c0 >> 4) + cc;
      bf16x8 kf0 = *(const bf16x8*)&hc[cb * 1024 + lane8];
      bf16x8 kf1 = *(const bf16x8*)&hc[cb * 1024 + 512 + lane8];
      bf16x8 vv0 = *(const bf16x8*)&hv[cb * 1024 + lane8];
      bf16x8 vv1 = *(const bf16x8*)&hv[cb * 1024 + 512 + lane8];
      bf16x4 va[4];
      split8(vv0, &va[0], &va[1]);
      split8(vv1, &va[2], &va[3]);
      #pragma unroll
      for (int g = 0; g < 2; ++g) {
        f32x4 s = MFMA_QK(kf0, qf[g][0], ZERO4);
        s = MFMA_QK(kf1, qf[g][1], s);
        unsigned nib = (((cc & 2) ? mhi[g] : mlo[g]) >> (((cc & 1) << 4) + qd4)) & 0xFu;
        f32x4 p;
        #pragma unroll
        for (int rr = 0; rr < 4; ++rr) {
          float e = EXP2(__builtin_fmaf(s[rr], SCALE_LOG2E, linv[g]));
          p[rr] = (nib & (1u << rr)) ? e : 0.f;
        }
        union { unsigned u2[2]; bf16x4 v4; uint2 d; } pk;
        pk.u2[0] = pack2(p[0], p[1]);
        pk.u2[1] = pack2(p[2], p[3]);
        *(uint2*)&s_part[buf][h][g*16 + l15][cc*16 + qd4] = pk.d;
        #pragma unroll
        for (int dc = 0; dc < 4; ++dc)
          oacc[g][dc] = MFMA_PV(va[dc], pk.v4, oacc[g][dc]);
      }
    }
    __syncthreads();   // s_part[buf] complete; prior reads of other buffer done
    {
      f32x4 macc = ZERO4;
      #pragma unroll
      for (int hh = 0; hh < 8; ++hh) {
        uint2 pv = *(const uint2*)&s_part[buf][hh][cr][cc4];
        union { unsigned u; float f; } a0, a1, a2, a3;
        a0.u = pv.x << 16; a1.u = pv.x & 0xffff0000u;
        a2.u = pv.y << 16; a3.u = pv.y & 0xffff0000u;
        macc[0] += a0.f; macc[1] += a1.f; macc[2] += a2.f; macc[3] += a3.f;
      }
      macc *= 0.125f;
      *(f32x4*)&mean_out[((size_t)b * NSEQ + n0 + cr) * NSEQ + c0 + cc4] = macc;
    }
  }

  PV_EPILOGUE_GUARD();
  #pragma unroll
  for (int g = 0; g < 2; ++g)
    #pragma unroll
    for (int dc = 0; dc < 4; ++dc) {
      size_t token = (size_t)b * NSEQ + n0 + g*16 + l15;
      f16x4 o;
      #pragma unroll
      for (int rr = 0; rr < 4; ++rr) o[rr] = (_Float16)oacc[g][dc][rr];
      *(f16x4*)&o_part[(size_t)quarter * O_ELEMS + token * MD + h*64 + dc*16 + qd4] = o;
    }
}

// ============================================================================
// LayerNorm over model dim; sums the 4 fp16 column-quarter O partials.
// ============================================================================
__global__ __launch_bounds__(256)
void ln_kernel(const _Float16* __restrict__ o_part, const float* __restrict__ gamma,
               const float* __restrict__ beta, float* __restrict__ out) {
  const int row = blockIdx.x, t = threadIdx.x;
  const size_t base = (size_t)row * MD + 2 * t;
  float v0 = 0.f, v1 = 0.f;
  #pragma unroll
  for (int q = 0; q < NSPLIT_A; ++q) {
    f16x2 x = *(const f16x2*)&o_part[(size_t)q * O_ELEMS + base];
    v0 += (float)x[0]; v1 += (float)x[1];
  }
  float s = v0 + v1, sq = v0 * v0 + v1 * v1;
  for (int m = 1; m < 64; m <<= 1) { s += __shfl_xor(s, m); sq += __shfl_xor(sq, m); }
  __shared__ float rs[4], rq[4];
  if ((t & 63) == 0) { rs[t >> 6] = s; rq[t >> 6] = sq; }
  __syncthreads();
  s = rs[0] + rs[1] + rs[2] + rs[3];
  sq = rq[0] + rq[1] + rq[2] + rq[3];
  float mu = s * (1.f / MD);
  float var = sq * (1.f / MD) - mu * mu;
  float rstd = rsqrtf(var + 1e-5f);
  f32x2 g2 = *(const f32x2*)&gamma[2 * t];
  f32x2 b2 = *(const f32x2*)&beta[2 * t];
  f32x2 o;
  o[0] = (v0 - mu) * rstd * g2[0] + b2[0];
  o[1] = (v1 - mu) * rstd * g2[1] + b2[1];
  *(f32x2*)&out[base] = o;
}

// ============================================================================
extern "C" void kernel_launch(void* const* d_in, const int* in_sizes, int n_in,
                              void* d_out, int out_size, void* d_ws, size_t ws_size,
                              hipStream_t stream) {
  const float* x     = (const float*)d_in[0];
  const int*   adj   = (const int*)d_in[1];
  const float* W     = (const float*)d_in[2];
  const float* Wb    = (const float*)d_in[3];
  const float* gamma = (const float*)d_in[4];
  const float* beta  = (const float*)d_in[5];
  float* out = (float*)d_out;

  unsigned short* xb  = (unsigned short*)d_ws;              // 4 MB
  unsigned short* wt  = xb + XB_ELEMS;                      // 0.5 MB
  unsigned short* h_c = wt + WT_ELEMS;                      // 4 MB
  unsigned short* h_v = h_c + HH_ELEMS;                     // 4 MB
  unsigned long long* mbits = (unsigned long long*)(h_v + HH_ELEMS);  // 1 MB
  float* l_part = (float*)(mbits + MB_ELEMS);               // 1 MB (8 partials)
  _Float16* o_part = (_Float16*)(l_part + NSPLIT_S * L_ELEMS);  // 16 MB (4 partials)

  cvt_kernel<<<2304, 256, 0, stream>>>(x, W, xb, wt);
  maskpack_kernel<<<8192, 1024, 0, stream>>>(adj, mbits);
  proj_kernel<<<dim3(64, 8), 256, 0, stream>>>(xb, wt, Wb, h_c, h_v);
  stats_kernel<<<dim3(128, NSPLIT_S), 512, 0, stream>>>(h_c, mbits, l_part);
  attn_kernel<<<dim3(128, NSPLIT_A), 512, 0, stream>>>(h_c, h_v, mbits, l_part, o_part,
                                                       out + (size_t)NTOK * MD);
  ln_kernel<<<NTOK, 256, 0, stream>>>(o_part, gamma, beta, out);
}